// Round 9
// baseline (468.316 us; speedup 1.0000x reference)
//
#include <hip/hip_runtime.h>
#include <hip/hip_bf16.h>
#include <stdint.h>

// Problem constants (fixed by the reference setup_inputs)
#define BATCH  16384
#define D_IN   1024
#define M_HID  4096
#define R_LORA 16
#define SCALING 2.0f   // ALPHA/R = 32/16

// R14: residue ledger (v1 ~= v4 ~= 95us despite opposite access patterns;
// v4's work is ~12us of I/O) => ~80us is fixed harness overhead; the lever is
// k_strip = 935 TF effective = the documented m97-structure ceiling (R7 TLP,
// R10 L2-pinning, R11 amortization all null). Escape path proven on this HW:
// 256^2-tile staged-GEMM schedule class (m201: 1563-1728 TF). This round
// ports it with compile-safe idioms only: reg-staged double-buffered LDS
// (T14 issue-early/write-late; compiler inserts the vmcnt via register dep),
// one barrier per K-chunk, XOR-unit swizzle u = r*8+(c8^(r&7)) carried in the
// GLOBAL layout (k_xprep/k_wprepT write tile-ordered) so staging loads are
// purely sequential and MFMA ds_reads are bank-balanced. Grid 64x16 with
// bijective XCD chunk swizzle (nwg=1024 % 8 == 0). acc[4][2] 32x32x16 frags,
// proven C/D mapping; fused relu+W2 fold + atomicAdd epilogue (proven).
// Fallback: ws < 40 MB -> exact R13 path (245us). ws >= 40 MB -> new path.

#define STRIP    64
#define NTHREADS 512

typedef __bf16 bf16x8 __attribute__((ext_vector_type(8)));
typedef float  f32x16 __attribute__((ext_vector_type(16)));

__device__ __forceinline__ unsigned f2bf(float f) {
    union { float f; unsigned u; } c; c.f = f;
    unsigned u = c.u;
    return ((u + 0x7FFFu + ((u >> 16) & 1u)) >> 16);
}

// ================= NEW PATH (ws >= 40 MiB) =================

// ---- k_xprep: x fp32 -> bf16, tile-ordered + swizzled; also out=b2 init ----
// xb tile (mt,kt): 256 rows x 64 K; 16-B unit u = r*8 + (c8 ^ (r&7)).
__global__ __launch_bounds__(256) void k_xprep(
    const float* __restrict__ xf, const float* __restrict__ b2,
    unsigned short* __restrict__ xb, float* __restrict__ out)
{
    const int tid  = threadIdx.x;
    const int tile = blockIdx.x;            // mt*16 + kt, 0..1023
    const int mt   = tile >> 4, kt = tile & 15;
    if (tile < 64) out[tile * 256 + tid] = b2[0];

    unsigned short* dst = xb + (size_t)tile * 16384;
    const float* src0 = xf + (size_t)(mt * 256) * D_IN + kt * 64;
#pragma unroll
    for (int i = 0; i < 8; ++i) {
        int u  = i * 256 + tid;
        int r  = u >> 3;
        int c8 = (u & 7) ^ (r & 7);
        const float* p = src0 + (size_t)r * D_IN + c8 * 8;
        float4 v0 = *(const float4*)(p);
        float4 v1 = *(const float4*)(p + 4);
        uint4 o;
        o.x = f2bf(v0.x) | (f2bf(v0.y) << 16);
        o.y = f2bf(v0.z) | (f2bf(v0.w) << 16);
        o.z = f2bf(v1.x) | (f2bf(v1.y) << 16);
        o.w = f2bf(v1.z) | (f2bf(v1.w) << 16);
        *(uint4*)(dst + (size_t)u * 8) = o;     // coalesced
    }
}

// ---- k_wprepT: v4 compute (coalesced reads, LDS transpose) -> tile layout ----
// wbT tile (nt,kt): 256 n-rows x 64 K, same unit swizzle as xb.
__global__ __launch_bounds__(256) void k_wprepT(
    const float* __restrict__ W0, const float* __restrict__ A,
    const float* __restrict__ Bl, unsigned short* __restrict__ wbT)
{
    __shared__ float A4[8192];                 // [r][h][lane] float4s
    __shared__ float Bs[512];
    __shared__ unsigned short floc[16384];     // 32 KiB, XOR row^(l&7)

    const int tid   = threadIdx.x;
    const int n32   = blockIdx.x >> 1;         // 0..127
    const int chalf = blockIdx.x & 1;
    const int col0  = chalf * 512;

    {
        const float4* Asrc = (const float4*)A;
#pragma unroll
        for (int i = 0; i < 8; ++i) {
            int idx = i * 256 + tid;
            int r = idx >> 7, h = (idx >> 6) & 1, ll = idx & 63;
            ((float4*)A4)[idx] = Asrc[r * 256 + (col0 >> 2) + ll * 2 + h];
        }
        Bs[tid]       = SCALING * Bl[n32 * 512 + tid];
        Bs[tid + 256] = SCALING * Bl[n32 * 512 + 256 + tid];
    }
    __syncthreads();

    const int w = tid >> 6;
    const int l = tid & 63;

    float acc[8][8];
#pragma unroll
    for (int jj = 0; jj < 8; ++jj) {
        const int row = w * 8 + jj;
        const float* p = W0 + (size_t)(n32 * 32 + row) * D_IN + col0 + l * 8;
        float4 v0 = *(const float4*)(p);
        float4 v1 = *(const float4*)(p + 4);
        acc[jj][0] = v0.x; acc[jj][1] = v0.y; acc[jj][2] = v0.z; acc[jj][3] = v0.w;
        acc[jj][4] = v1.x; acc[jj][5] = v1.y; acc[jj][6] = v1.z; acc[jj][7] = v1.w;
    }
#pragma unroll
    for (int r = 0; r < R_LORA; ++r) {
        float4 a0 = ((const float4*)A4)[r * 128 + l];
        float4 a1 = ((const float4*)A4)[r * 128 + 64 + l];
        const float av[8] = { a0.x, a0.y, a0.z, a0.w, a1.x, a1.y, a1.z, a1.w };
#pragma unroll
        for (int jj = 0; jj < 8; ++jj) {
            float s = Bs[(w * 8 + jj) * 16 + r];
#pragma unroll
            for (int k = 0; k < 8; ++k) acc[jj][k] += s * av[k];
        }
    }

#pragma unroll
    for (int jj = 0; jj < 8; ++jj) {
        const int row = w * 8 + jj;
        uint4 o;
        o.x = f2bf(acc[jj][0]) | (f2bf(acc[jj][1]) << 16);
        o.y = f2bf(acc[jj][2]) | (f2bf(acc[jj][3]) << 16);
        o.z = f2bf(acc[jj][4]) | (f2bf(acc[jj][5]) << 16);
        o.w = f2bf(acc[jj][6]) | (f2bf(acc[jj][7]) << 16);
        *(uint4*)((char*)floc + l * 512 + ((row ^ (l & 7)) << 4)) = o;
    }
    __syncthreads();

    // copy-out in target-linear order: per ktl a 4 KB contiguous run
    const int nt   = n32 >> 3;
    const int base = (n32 & 7) * 32;           // n_local base
#pragma unroll
    for (int ktl = 0; ktl < 8; ++ktl) {
        const int kt = chalf * 8 + ktl;
        const int rl = tid >> 3;               // 0..31
        const int c8 = (tid & 7) ^ (rl & 7);   // n_l&7 == rl&7 (base%32==0)
        uint4 v = *(const uint4*)((const char*)floc
                  + (ktl * 8 + c8) * 512 + ((rl ^ c8) << 4));
        *(uint4*)(wbT + ((size_t)(nt * 16 + kt) * 2048 + base * 8 + tid) * 8) = v;
    }
}

// ---- k_gemm: 256x256 tile, K=1024 in 16 chunks, fused relu+W2 fold ----
__global__ __launch_bounds__(512, 2) void k_gemm(
    const unsigned short* __restrict__ xb, const unsigned short* __restrict__ wbT,
    const float* __restrict__ b0, const float* __restrict__ W2,
    float* __restrict__ out)
{
    __shared__ unsigned short Abuf[2][16384];  // 2 x 32 KiB
    __shared__ unsigned short Bbuf[2][16384];  // 2 x 32 KiB
    __shared__ float red[8][128];              // 4 KiB

    const int tid  = threadIdx.x;
    const int lane = tid & 63, wave = tid >> 6;
    const int rl   = lane & 31, half = lane >> 5;
    const int wm   = wave >> 2, wn = wave & 3;
    const int rx   = rl & 7;

    // bijective XCD chunk swizzle (nwg=1024, 8 XCDs)
    const int swz = (blockIdx.x & 7) * 128 + (blockIdx.x >> 3);
    const int nt  = swz >> 6, mt = swz & 63;

    const unsigned short* asrc = xb  + (size_t)(mt * 16) * 16384;
    const unsigned short* bsrc = wbT + (size_t)(nt * 16) * 16384;

    uint4 ra[4], rb[4];
#define GLOAD(KT)                                                            \
    {                                                                        \
        const uint4* ap = (const uint4*)(asrc + (size_t)(KT) * 16384);       \
        const uint4* bp = (const uint4*)(bsrc + (size_t)(KT) * 16384);       \
        _Pragma("unroll")                                                    \
        for (int i_ = 0; i_ < 4; ++i_) {                                     \
            ra[i_] = ap[i_ * 512 + tid];                                     \
            rb[i_] = bp[i_ * 512 + tid];                                     \
        }                                                                    \
    }
#define DSWRITE(BUF)                                                         \
    {                                                                        \
        _Pragma("unroll")                                                    \
        for (int i_ = 0; i_ < 4; ++i_) {                                     \
            *(uint4*)((char*)Abuf[BUF] + (i_ * 512 + tid) * 16) = ra[i_];    \
            *(uint4*)((char*)Bbuf[BUF] + (i_ * 512 + tid) * 16) = rb[i_];    \
        }                                                                    \
    }

    GLOAD(0); DSWRITE(0); __syncthreads();
    GLOAD(1);                                   // in flight under kt=0 MFMA

    f32x16 acc[4][2] = {};

    for (int kt = 0; kt < 16; ++kt) {
        const char* Ap = (const char*)Abuf[kt & 1] + (wm * 128 + rl) * 128;
        const char* Bp = (const char*)Bbuf[kt & 1] + (wn * 64 + rl) * 128;
#pragma unroll
        for (int s = 0; s < 4; ++s) {
            const int off = ((2 * s + half) ^ rx) << 4;
            bf16x8 a0  = *(const bf16x8*)(Ap + off);
            bf16x8 a1  = *(const bf16x8*)(Ap + 4096  + off);
            bf16x8 a2  = *(const bf16x8*)(Ap + 8192  + off);
            bf16x8 a3  = *(const bf16x8*)(Ap + 12288 + off);
            bf16x8 bv0 = *(const bf16x8*)(Bp + off);
            bf16x8 bv1 = *(const bf16x8*)(Bp + 4096  + off);
            acc[0][0] = __builtin_amdgcn_mfma_f32_32x32x16_bf16(a0, bv0, acc[0][0], 0, 0, 0);
            acc[0][1] = __builtin_amdgcn_mfma_f32_32x32x16_bf16(a0, bv1, acc[0][1], 0, 0, 0);
            acc[1][0] = __builtin_amdgcn_mfma_f32_32x32x16_bf16(a1, bv0, acc[1][0], 0, 0, 0);
            acc[1][1] = __builtin_amdgcn_mfma_f32_32x32x16_bf16(a1, bv1, acc[1][1], 0, 0, 0);
            acc[2][0] = __builtin_amdgcn_mfma_f32_32x32x16_bf16(a2, bv0, acc[2][0], 0, 0, 0);
            acc[2][1] = __builtin_amdgcn_mfma_f32_32x32x16_bf16(a2, bv1, acc[2][1], 0, 0, 0);
            acc[3][0] = __builtin_amdgcn_mfma_f32_32x32x16_bf16(a3, bv0, acc[3][0], 0, 0, 0);
            acc[3][1] = __builtin_amdgcn_mfma_f32_32x32x16_bf16(a3, bv1, acc[3][1], 0, 0, 0);
        }
        if (kt < 15) {
            DSWRITE((kt & 1) ^ 1);              // compiler waits vmcnt via reg dep
            __syncthreads();                    // one barrier per K-chunk
            if (kt < 14) GLOAD(kt + 2);         // hidden under next MFMA phase
        }
    }

    // epilogue: relu(h+b0) dot W2, 32-lane shuffle-reduce, cross-wave sum
    // C/D layout (m74/m101): col = lane&31, row = (r&3) + 8*(r>>2) + 4*half
    const int n0 = nt * 256 + wn * 64;
    const float w2a = W2[n0 + rl],      b0a = b0[n0 + rl];
    const float w2b = W2[n0 + 32 + rl], b0b = b0[n0 + 32 + rl];
#pragma unroll
    for (int ti = 0; ti < 4; ++ti)
#pragma unroll
        for (int r = 0; r < 16; ++r) {
            float p = fmaxf(acc[ti][0][r] + b0a, 0.f) * w2a
                    + fmaxf(acc[ti][1][r] + b0b, 0.f) * w2b;
#pragma unroll
            for (int m = 1; m <= 16; m <<= 1)
                p += __shfl_xor(p, m, 64);
            if (rl == 0)
                red[wave][ti * 32 + (r & 3) + 8 * (r >> 2) + 4 * half] = p;
        }
    __syncthreads();
    if (tid < 256) {
        const int wmf = tid >> 7, q = tid & 127;
        float s = red[wmf * 4 + 0][q] + red[wmf * 4 + 1][q]
                + red[wmf * 4 + 2][q] + red[wmf * 4 + 3][q];
        atomicAdd(&out[(size_t)mt * 256 + tid], s);   // 16 adds/row (nt blocks)
    }
#undef GLOAD
#undef DSWRITE
}

// ================= FALLBACK PATH (ws >= 8 MiB): exact R13 =================

__global__ __launch_bounds__(256) void k_wprep(
    const float* __restrict__ W0, const float* __restrict__ A,
    const float* __restrict__ Bl, unsigned short* __restrict__ wb)
{
    __shared__ float A4[8192];
    __shared__ float Bs[512];
    __shared__ unsigned short floc[16384];

    const int tid   = threadIdx.x;
    const int n32   = blockIdx.x >> 1;
    const int chalf = blockIdx.x & 1;
    const int col0  = chalf * 512;

    {
        const float4* Asrc = (const float4*)A;
#pragma unroll
        for (int i = 0; i < 8; ++i) {
            int idx = i * 256 + tid;
            int r = idx >> 7, h = (idx >> 6) & 1, ll = idx & 63;
            ((float4*)A4)[idx] = Asrc[r * 256 + (col0 >> 2) + ll * 2 + h];
        }
        Bs[tid]       = SCALING * Bl[n32 * 512 + tid];
        Bs[tid + 256] = SCALING * Bl[n32 * 512 + 256 + tid];
    }
    __syncthreads();

    const int w = tid >> 6;
    const int l = tid & 63;

    float acc[8][8];
#pragma unroll
    for (int jj = 0; jj < 8; ++jj) {
        const int row = w * 8 + jj;
        const float* p = W0 + (size_t)(n32 * 32 + row) * D_IN + col0 + l * 8;
        float4 v0 = *(const float4*)(p);
        float4 v1 = *(const float4*)(p + 4);
        acc[jj][0] = v0.x; acc[jj][1] = v0.y; acc[jj][2] = v0.z; acc[jj][3] = v0.w;
        acc[jj][4] = v1.x; acc[jj][5] = v1.y; acc[jj][6] = v1.z; acc[jj][7] = v1.w;
    }
#pragma unroll
    for (int r = 0; r < R_LORA; ++r) {
        float4 a0 = ((const float4*)A4)[r * 128 + l];
        float4 a1 = ((const float4*)A4)[r * 128 + 64 + l];
        const float av[8] = { a0.x, a0.y, a0.z, a0.w, a1.x, a1.y, a1.z, a1.w };
#pragma unroll
        for (int jj = 0; jj < 8; ++jj) {
            float s = Bs[(w * 8 + jj) * 16 + r];
#pragma unroll
            for (int k = 0; k < 8; ++k) acc[jj][k] += s * av[k];
        }
    }
#pragma unroll
    for (int jj = 0; jj < 8; ++jj) {
        const int row = w * 8 + jj;
        uint4 o;
        o.x = f2bf(acc[jj][0]) | (f2bf(acc[jj][1]) << 16);
        o.y = f2bf(acc[jj][2]) | (f2bf(acc[jj][3]) << 16);
        o.z = f2bf(acc[jj][4]) | (f2bf(acc[jj][5]) << 16);
        o.w = f2bf(acc[jj][6]) | (f2bf(acc[jj][7]) << 16);
        *(uint4*)((char*)floc + l * 512 + ((row ^ (l & 7)) << 4)) = o;
    }
    __syncthreads();

    unsigned short* gdst = wb + (size_t)n32 * 32768 + chalf * 16384;
#pragma unroll
    for (int i = 0; i < 8; ++i) {
        int L16 = i * 256 + tid;
        int ll = L16 >> 5, rr = L16 & 31;
        uint4 v = *(const uint4*)((const char*)floc + ll * 512 + ((rr ^ (ll & 7)) << 4));
        *(uint4*)(gdst + (size_t)L16 * 8) = v;
    }
}

__global__ __launch_bounds__(NTHREADS, 2) void k_strip(
    const float* __restrict__ xf, const unsigned short* __restrict__ wb,
    const float* __restrict__ b0, const float* __restrict__ W2,
    const float* __restrict__ b2, float* __restrict__ out)
{
    __shared__ unsigned short As[STRIP * D_IN];
    __shared__ float red[8][STRIP];

    const int tid  = threadIdx.x;
    const int lane = tid & 63;
    const int wave = tid >> 6;
    const int rl   = lane & 31;
    const int half = lane >> 5;
    const int row0 = blockIdx.x * STRIP;

    {
        const int r  = tid >> 3;
        const int c0 = tid & 7;
        const float* xr = xf + (size_t)(row0 + r) * D_IN;
#pragma unroll
        for (int i = 0; i < 16; ++i) {
            int c = i * 8 + c0;
            float4 v0 = *(const float4*)(xr + c * 8);
            float4 v1 = *(const float4*)(xr + c * 8 + 4);
            uint4 o;
            o.x = f2bf(v0.x) | (f2bf(v0.y) << 16);
            o.y = f2bf(v0.z) | (f2bf(v0.w) << 16);
            o.z = f2bf(v1.x) | (f2bf(v1.y) << 16);
            o.w = f2bf(v1.z) | (f2bf(v1.w) << 16);
            *(uint4*)(&As[c * 512 + r * 8]) = o;
        }
    }
    __syncthreads();

    float rowpart[2][16];
#pragma unroll
    for (int ti = 0; ti < 2; ++ti)
#pragma unroll
        for (int r = 0; r < 16; ++r) rowpart[ti][r] = 0.f;

    for (int pass = 0; pass < 8; ++pass) {
        const int n0 = wave * 64 + pass * 512;
        const float w2a = W2[n0 + rl],      b0a = b0[n0 + rl];
        const float w2b = W2[n0 + 32 + rl], b0b = b0[n0 + 32 + rl];
        const int n32 = wave * 2 + pass * 16;
        const unsigned short* w0p = wb + (size_t)n32 * 32768 + half * 256 + rl * 8;
        const unsigned short* w1p = w0p + 32768;

        f32x16 acc[2][2] = {};
        bf16x8 wf0[4], wf1[4];
#pragma unroll
        for (int p = 0; p < 4; ++p) {
            wf0[p] = *(const bf16x8*)(w0p + p * 512);
            wf1[p] = *(const bf16x8*)(w1p + p * 512);
        }

#pragma unroll 4
        for (int kk = 0; kk < 64; ++kk) {
            const int cur = kk & 3;
            const int coff = (kk * 2 + half) * 512 + rl * 8;
            bf16x8 af0 = *(const bf16x8*)(&As[coff]);
            bf16x8 af1 = *(const bf16x8*)(&As[coff + 256]);
            bf16x8 w0c = wf0[cur], w1c = wf1[cur];
            if (kk < 60) {
                wf0[cur] = *(const bf16x8*)(w0p + (kk + 4) * 512);
                wf1[cur] = *(const bf16x8*)(w1p + (kk + 4) * 512);
            }
            acc[0][0] = __builtin_amdgcn_mfma_f32_32x32x16_bf16(af0, w0c, acc[0][0], 0, 0, 0);
            acc[0][1] = __builtin_amdgcn_mfma_f32_32x32x16_bf16(af0, w1c, acc[0][1], 0, 0, 0);
            acc[1][0] = __builtin_amdgcn_mfma_f32_32x32x16_bf16(af1, w0c, acc[1][0], 0, 0, 0);
            acc[1][1] = __builtin_amdgcn_mfma_f32_32x32x16_bf16(af1, w1c, acc[1][1], 0, 0, 0);
        }

#pragma unroll
        for (int ti = 0; ti < 2; ++ti)
#pragma unroll
            for (int r = 0; r < 16; ++r)
                rowpart[ti][r] += fmaxf(acc[ti][0][r] + b0a, 0.f) * w2a
                                + fmaxf(acc[ti][1][r] + b0b, 0.f) * w2b;
    }

#pragma unroll
    for (int ti = 0; ti < 2; ++ti)
#pragma unroll
        for (int r = 0; r < 16; ++r) {
            float p = rowpart[ti][r];
#pragma unroll
            for (int m = 1; m <= 16; m <<= 1)
                p += __shfl_xor(p, m, 64);
            if (rl == 0)
                red[wave][ti * 32 + (r & 3) + 8 * (r >> 2) + 4 * half] = p;
        }
    __syncthreads();
    if (tid < STRIP) {
        float s = b2[0];
#pragma unroll
        for (int w = 0; w < 8; ++w) s += red[w][tid];
        out[row0 + tid] = s;
    }
}

// ---------------- naive fallback (correctness only; ws too small) -------------
__global__ __launch_bounds__(256) void k_naive(
    const float* __restrict__ x, const float* __restrict__ W0,
    const float* __restrict__ b0, const float* __restrict__ A,
    const float* __restrict__ Bl, const float* __restrict__ W2,
    const float* __restrict__ b2, float* __restrict__ out)
{
    __shared__ float xs[D_IN];
    int b = blockIdx.x;
    for (int d = threadIdx.x; d < D_IN; d += 256) xs[d] = x[(size_t)b * D_IN + d];
    __syncthreads();
    float part = 0.f;
    for (int m = threadIdx.x; m < M_HID; m += 256) {
        float h = b0[m];
        const float* wr = W0 + (size_t)m * D_IN;
        const float* brow = Bl + m * R_LORA;
        for (int d = 0; d < D_IN; ++d) {
            float w = wr[d];
            for (int r = 0; r < R_LORA; ++r) w += SCALING * brow[r] * A[r * D_IN + d];
            h += xs[d] * w;
        }
        part += fmaxf(h, 0.f) * W2[m];
    }
    __shared__ float sred[256];
    sred[threadIdx.x] = part;
    __syncthreads();
    for (int s = 128; s > 0; s >>= 1) {
        if (threadIdx.x < s) sred[threadIdx.x] += sred[threadIdx.x + s];
        __syncthreads();
    }
    if (threadIdx.x == 0) out[b] = sred[0] + b2[0];
}

// ---------------- host ----------------
extern "C" void kernel_launch(void* const* d_in, const int* in_sizes, int n_in,
                              void* d_out, int out_size, void* d_ws, size_t ws_size,
                              hipStream_t stream) {
    const float* x  = (const float*)d_in[0];
    const float* W0 = (const float*)d_in[1];
    const float* b0 = (const float*)d_in[2];
    const float* A  = (const float*)d_in[3];
    const float* Bl = (const float*)d_in[4];
    const float* W2 = (const float*)d_in[5];
    const float* b2 = (const float*)d_in[6];
    float* out = (float*)d_out;

    const size_t wb_bytes = (size_t)M_HID * D_IN * 2;        // 8 MiB
    const size_t xb_bytes = (size_t)BATCH * D_IN * 2;        // 32 MiB

    if (ws_size >= wb_bytes + xb_bytes) {
        unsigned short* wbT = (unsigned short*)d_ws;
        unsigned short* xb  = (unsigned short*)((char*)d_ws + wb_bytes);
        hipLaunchKernelGGL(k_xprep, dim3(1024), dim3(256), 0, stream,
                           x, b2, xb, out);
        hipLaunchKernelGGL(k_wprepT, dim3(M_HID / 32 * 2), dim3(256), 0, stream,
                           W0, A, Bl, wbT);
        hipLaunchKernelGGL(k_gemm, dim3(1024), dim3(512), 0, stream,
                           xb, wbT, b0, W2, out);
    } else if (ws_size >= wb_bytes) {
        unsigned short* wb = (unsigned short*)d_ws;
        hipLaunchKernelGGL(k_wprep, dim3(M_HID / 32 * 2), dim3(256), 0, stream,
                           W0, A, Bl, wb);
        hipLaunchKernelGGL(k_strip, dim3(BATCH / STRIP), dim3(NTHREADS), 0, stream,
                           x, wb, b0, W2, b2, out);
    } else {
        hipLaunchKernelGGL(k_naive, dim3(BATCH), dim3(256), 0, stream,
                           x, W0, b0, A, Bl, W2, b2, out);
    }
}

// Round 10
// 251.315 us; speedup vs baseline: 1.8635x; 1.8635x over previous
//
#include <hip/hip_runtime.h>
#include <hip/hip_bf16.h>
#include <stdint.h>

// Problem constants (fixed by the reference setup_inputs)
#define BATCH  16384
#define D_IN   1024
#define M_HID  4096
#define R_LORA 16
#define SCALING 2.0f   // ALPHA/R = 32/16

// R15 = revert to R13, the best measured configuration (245.1 us total).
// Rationale (counters, R0-R14):
//  - k_strip (R0/R5 body): 147-161 us = 935 TF = its geometric roofline:
//    intensity 64 FLOP/B (64-row strip) x ~23 B/cyc/CU per-CU streaming
//    delivery (same constant measured for m97: 22, m201: 19 B/cyc/CU)
//    x 256 CU x 2.4 GHz ~= 900-940 TF. TLP (R7), L2 pinning (R8/R10),
//    row-amortization (R6/R11), 256^2 GEMM (R14: scratch spill, WRITE
//    842 MB) all regressed or nulled.
//  - k_wprep v4 (LDS-transposed, both global sides coalesced): ~13 us,
//    near its I/O floor.
//  - Remaining ~84 us of total is dispatch/harness overhead (memsets +
//    3-kernel launch chain), outside kernel control.
// Break-even for a 256^2 GEMM replacement needs >1040 TF effective; the
// compile-safe m97-class schedule measures 792 TF at 256^2 (guide), so
// only the race-prone 8-phase inline-asm schedule could win -- not
// attemptable headlessly with confidence. This is the practical optimum.

#define STRIP    64
#define NTHREADS 512

typedef __bf16 bf16x8 __attribute__((ext_vector_type(8)));
typedef float  f32x16 __attribute__((ext_vector_type(16)));

__device__ __forceinline__ unsigned f2bf(float f) {
    union { float f; unsigned u; } c; c.f = f;
    unsigned u = c.u;
    return ((u + 0x7FFFu + ((u >> 16) & 1u)) >> 16);
}

// ---------------- prep v4: W_eff -> fragment-ordered bf16, LDS transpose ------
// Global layout (shorts): n32*32768 + c*256 + rl*8 + j = W_eff[n32*32+rl][c*8+j]
// Block = (n32, chalf): rows n32*32..+32, cols chalf*512..+512.
// Output region = shorts [n32*32768 + chalf*16384, +16384) -- contiguous 32 KB.
__global__ __launch_bounds__(256) void k_wprep(
    const float* __restrict__ W0, const float* __restrict__ A,
    const float* __restrict__ Bl, unsigned short* __restrict__ wb)
{
    __shared__ float A4[8192];                 // 32 KiB: [r][h][lane] float4s
    __shared__ float Bs[512];                  // 32 rows x 16 r, pre-scaled
    __shared__ unsigned short floc[16384];     // 32 KiB bf16 tile, XOR-swizzled

    const int tid   = threadIdx.x;             // 256 threads
    const int n32   = blockIdx.x >> 1;         // 0..127
    const int chalf = blockIdx.x & 1;
    const int col0  = chalf * 512;

    // ---- stage A-half + pre-scaled B into LDS ----
    {
        const float4* Asrc = (const float4*)A;
#pragma unroll
        for (int i = 0; i < 8; ++i) {
            int idx = i * 256 + tid;           // float4-linear: r*128 + h*64 + l
            int r = idx >> 7, h = (idx >> 6) & 1, ll = idx & 63;
            ((float4*)A4)[idx] = Asrc[r * 256 + (col0 >> 2) + ll * 2 + h];
        }
        Bs[tid]       = SCALING * Bl[n32 * 512 + tid];
        Bs[tid + 256] = SCALING * Bl[n32 * 512 + 256 + tid];
    }
    __syncthreads();

    const int w = tid >> 6;                    // wave 0..3 -> rows w*8..w*8+7
    const int l = tid & 63;                    // col octet within the half

    // ---- compute 8x8 W_eff patch; W0 reads coalesced (2 KB per wave-row) ----
    float acc[8][8];
#pragma unroll
    for (int jj = 0; jj < 8; ++jj) {
        const int row = w * 8 + jj;
        const float* p = W0 + (size_t)(n32 * 32 + row) * D_IN + col0 + l * 8;
        float4 v0 = *(const float4*)(p);
        float4 v1 = *(const float4*)(p + 4);
        acc[jj][0] = v0.x; acc[jj][1] = v0.y; acc[jj][2] = v0.z; acc[jj][3] = v0.w;
        acc[jj][4] = v1.x; acc[jj][5] = v1.y; acc[jj][6] = v1.z; acc[jj][7] = v1.w;
    }
#pragma unroll
    for (int r = 0; r < R_LORA; ++r) {
        float4 a0 = ((const float4*)A4)[r * 128 + l];        // conflict-free
        float4 a1 = ((const float4*)A4)[r * 128 + 64 + l];
        const float av[8] = { a0.x, a0.y, a0.z, a0.w, a1.x, a1.y, a1.z, a1.w };
#pragma unroll
        for (int jj = 0; jj < 8; ++jj) {
            float s = Bs[(w * 8 + jj) * 16 + r];             // wave-uniform bcast
#pragma unroll
            for (int k = 0; k < 8; ++k) acc[jj][k] += s * av[k];
        }
    }

    // ---- pack bf16, store into floc with XOR swizzle (conflict-free) ----
#pragma unroll
    for (int jj = 0; jj < 8; ++jj) {
        const int row = w * 8 + jj;
        uint4 o;
        o.x = f2bf(acc[jj][0]) | (f2bf(acc[jj][1]) << 16);
        o.y = f2bf(acc[jj][2]) | (f2bf(acc[jj][3]) << 16);
        o.z = f2bf(acc[jj][4]) | (f2bf(acc[jj][5]) << 16);
        o.w = f2bf(acc[jj][6]) | (f2bf(acc[jj][7]) << 16);
        *(uint4*)((char*)floc + l * 512 + ((row ^ (l & 7)) << 4)) = o;
    }
    __syncthreads();

    // ---- linear copy-out: LDS-linear == global-fragment-linear; 4 KB/wave ----
    unsigned short* gdst = wb + (size_t)n32 * 32768 + chalf * 16384;
#pragma unroll
    for (int i = 0; i < 8; ++i) {
        int L16 = i * 256 + tid;               // 16-byte unit index
        int ll = L16 >> 5, rr = L16 & 31;      // byte = ll*512 + rr*16 (linear)
        uint4 v = *(const uint4*)((const char*)floc + ll * 512 + ((rr ^ (ll & 7)) << 4));
        *(uint4*)(gdst + (size_t)L16 * 8) = v;
    }
}

// ---------------- main fused kernel (Round-0 body, measured 147-161us) --------
__global__ __launch_bounds__(NTHREADS, 2) void k_strip(
    const float* __restrict__ xf, const unsigned short* __restrict__ wb,
    const float* __restrict__ b0, const float* __restrict__ W2,
    const float* __restrict__ b2, float* __restrict__ out)
{
    // x strip, chunk-major: As[c*512 + r*8 + j] = x_bf16[row0+r][c*8+j]
    __shared__ unsigned short As[STRIP * D_IN];   // 128 KiB
    __shared__ float red[8][STRIP];               // 2 KiB cross-wave reduce

    const int tid  = threadIdx.x;
    const int lane = tid & 63;
    const int wave = tid >> 6;
    const int rl   = lane & 31;
    const int half = lane >> 5;
    const int row0 = blockIdx.x * STRIP;

    // ---- phase 1: x fp32 -> bf16 into resident LDS strip (coalesced reads;
    //      8-way LDS write conflicts are one-time, off the critical path) ----
    {
        const int r  = tid >> 3;                  // 0..63
        const int c0 = tid & 7;
        const float* xr = xf + (size_t)(row0 + r) * D_IN;
#pragma unroll
        for (int i = 0; i < 16; ++i) {
            int c = i * 8 + c0;
            float4 v0 = *(const float4*)(xr + c * 8);
            float4 v1 = *(const float4*)(xr + c * 8 + 4);
            uint4 o;
            o.x = f2bf(v0.x) | (f2bf(v0.y) << 16);
            o.y = f2bf(v0.z) | (f2bf(v0.w) << 16);
            o.z = f2bf(v1.x) | (f2bf(v1.y) << 16);
            o.w = f2bf(v1.z) | (f2bf(v1.w) << 16);
            *(uint4*)(&As[c * 512 + r * 8]) = o;
        }
    }
    __syncthreads();   // the only barrier before the final reduce

    float rowpart[2][16];
#pragma unroll
    for (int ti = 0; ti < 2; ++ti)
#pragma unroll
        for (int r = 0; r < 16; ++r) rowpart[ti][r] = 0.f;

    // ---- main: 8 passes x (K-loop with zero barriers) ----
    for (int pass = 0; pass < 8; ++pass) {
        const int n0 = wave * 64 + pass * 512;
        const float w2a = W2[n0 + rl],      b0a = b0[n0 + rl];
        const float w2b = W2[n0 + 32 + rl], b0b = b0[n0 + 32 + rl];
        const int n32 = wave * 2 + pass * 16;
        const unsigned short* w0p = wb + (size_t)n32 * 32768 + half * 256 + rl * 8;
        const unsigned short* w1p = w0p + 32768;

        f32x16 acc[2][2] = {};
        bf16x8 wf0[4], wf1[4];
#pragma unroll
        for (int p = 0; p < 4; ++p) {             // distance-4 register prefetch
            wf0[p] = *(const bf16x8*)(w0p + p * 512);
            wf1[p] = *(const bf16x8*)(w1p + p * 512);
        }

#pragma unroll 4
        for (int kk = 0; kk < 64; ++kk) {
            const int cur = kk & 3;
            const int coff = (kk * 2 + half) * 512 + rl * 8;
            bf16x8 af0 = *(const bf16x8*)(&As[coff]);        // rows 0..31
            bf16x8 af1 = *(const bf16x8*)(&As[coff + 256]);  // rows 32..63
            bf16x8 w0c = wf0[cur], w1c = wf1[cur];
            if (kk < 60) {
                wf0[cur] = *(const bf16x8*)(w0p + (kk + 4) * 512);
                wf1[cur] = *(const bf16x8*)(w1p + (kk + 4) * 512);
            }
            acc[0][0] = __builtin_amdgcn_mfma_f32_32x32x16_bf16(af0, w0c, acc[0][0], 0, 0, 0);
            acc[0][1] = __builtin_amdgcn_mfma_f32_32x32x16_bf16(af0, w1c, acc[0][1], 0, 0, 0);
            acc[1][0] = __builtin_amdgcn_mfma_f32_32x32x16_bf16(af1, w0c, acc[1][0], 0, 0, 0);
            acc[1][1] = __builtin_amdgcn_mfma_f32_32x32x16_bf16(af1, w1c, acc[1][1], 0, 0, 0);
        }

        // fold this pass: relu(h + bias) dot W2, accumulate per-lane
#pragma unroll
        for (int ti = 0; ti < 2; ++ti)
#pragma unroll
            for (int r = 0; r < 16; ++r)
                rowpart[ti][r] += fmaxf(acc[ti][0][r] + b0a, 0.f) * w2a
                                + fmaxf(acc[ti][1][r] + b0b, 0.f) * w2b;
    }

    // ---- final: shuffle-reduce over 32 col-lanes, cross-wave sum via LDS ----
    // C/D layout (m74/m101): col = lane&31, row = (r&3) + 8*(r>>2) + 4*half
#pragma unroll
    for (int ti = 0; ti < 2; ++ti)
#pragma unroll
        for (int r = 0; r < 16; ++r) {
            float p = rowpart[ti][r];
#pragma unroll
            for (int m = 1; m <= 16; m <<= 1)
                p += __shfl_xor(p, m, 64);        // stays within each 32-half
            if (rl == 0)
                red[wave][ti * 32 + (r & 3) + 8 * (r >> 2) + 4 * half] = p;
        }
    __syncthreads();
    if (tid < STRIP) {
        float s = b2[0];
#pragma unroll
        for (int w = 0; w < 8; ++w) s += red[w][tid];
        out[row0 + tid] = s;
    }
}

// ---------------- naive fallback (correctness only; ws too small) ----------------
__global__ __launch_bounds__(256) void k_naive(
    const float* __restrict__ x, const float* __restrict__ W0,
    const float* __restrict__ b0, const float* __restrict__ A,
    const float* __restrict__ Bl, const float* __restrict__ W2,
    const float* __restrict__ b2, float* __restrict__ out)
{
    __shared__ float xs[D_IN];
    int b = blockIdx.x;
    for (int d = threadIdx.x; d < D_IN; d += 256) xs[d] = x[(size_t)b * D_IN + d];
    __syncthreads();
    float part = 0.f;
    for (int m = threadIdx.x; m < M_HID; m += 256) {
        float h = b0[m];
        const float* wr = W0 + (size_t)m * D_IN;
        const float* brow = Bl + m * R_LORA;
        for (int d = 0; d < D_IN; ++d) {
            float w = wr[d];
            for (int r = 0; r < R_LORA; ++r) w += SCALING * brow[r] * A[r * D_IN + d];
            h += xs[d] * w;
        }
        part += fmaxf(h, 0.f) * W2[m];
    }
    __shared__ float sred[256];
    sred[threadIdx.x] = part;
    __syncthreads();
    for (int s = 128; s > 0; s >>= 1) {
        if (threadIdx.x < s) sred[threadIdx.x] += sred[threadIdx.x + s];
        __syncthreads();
    }
    if (threadIdx.x == 0) out[b] = sred[0] + b2[0];
}

// ---------------- host ----------------
extern "C" void kernel_launch(void* const* d_in, const int* in_sizes, int n_in,
                              void* d_out, int out_size, void* d_ws, size_t ws_size,
                              hipStream_t stream) {
    const float* x  = (const float*)d_in[0];
    const float* W0 = (const float*)d_in[1];
    const float* b0 = (const float*)d_in[2];
    const float* A  = (const float*)d_in[3];
    const float* Bl = (const float*)d_in[4];
    const float* W2 = (const float*)d_in[5];
    const float* b2 = (const float*)d_in[6];
    float* out = (float*)d_out;

    const size_t wb_bytes = (size_t)M_HID * D_IN * 2;   // 8 MiB fragment-ordered W_eff
    if (ws_size >= wb_bytes) {
        unsigned short* wb = (unsigned short*)d_ws;
        hipLaunchKernelGGL(k_wprep, dim3(256), dim3(256), 0, stream,
                           W0, A, Bl, wb);
        hipLaunchKernelGGL(k_strip, dim3(BATCH / STRIP), dim3(NTHREADS), 0, stream,
                           x, wb, b0, W2, b2, out);
    } else {
        hipLaunchKernelGGL(k_naive, dim3(BATCH), dim3(256), 0, stream,
                           x, W0, b0, A, Bl, W2, b2, out);
    }
}